// Round 17
// baseline (245.643 us; speedup 1.0000x reference)
//
#include <hip/hip_runtime.h>

// GLIFR RNN (B=64, T=200, IN=512, HID=1024, OUT=512), fp32 in/out, bf16 MFMA.
//
// DELAY=20 decouples the lateral matmul -> 10 chunks of 20 steps.
//
// Round 19: R18 base (best, 241.6) + T4 counted-vmcnt 3-deep pipeline in
// fused_chunk. R15's 2-buffer loop must drain the just-issued STAGE at every
// barrier (next COMPUTE needs it). 3 buffers prefetch 2 ahead: each barrier
// is `s_waitcnt vmcnt(9) lgkmcnt(0)` + raw s_barrier — waits only for the
// stage issued TWO phases ago (9 = uniform loads/wave/STAGE: A 20/4 + B
// 16/4), so the newest stage's loads fly across ~2 compute phases (~1000
// cyc >= HBM latency). Per-wave-uniform counts + barrier => all waves'
// older-stage loads complete (8-phase-template argument); lgkmcnt(0)
// closes the ds_read-vs-overwrite window; acc-init xproj loads are older
// than all STAGE loads so in-order vmcnt retiring keeps counts valid.
// BK=128, 8 sub-steps fully unrolled, named buffers (no runtime-indexed
// buffer arrays). Same k accumulation order as R18 -> bit-identical output.
//
// Workspace (~84 MB):
//   synb  bf16 [T,B,H]  @ 0          (26214400 B)  x_proj (read-only after GEMM)
//   state fp32 4x[B*H]  @ 52428800   (1048576 B)   volt, asc0, asc1, firing
//   F     bf16 [T,B,H]  @ 53477376   (26214400 B)  firing history
//     xb  bf16 [12800,512] overlays F (dead before first F write)
//   WinT  bf16 [H,IN]   @ 79691776   (1048576 B)
//   WlatT bf16 [H,H]    @ 80740352   (2097152 B)
//   WoutB bf16 [OUT,H]  @ 82837504   (1048576 B)

typedef float f32x4 __attribute__((ext_vector_type(4)));
typedef __bf16 bf16x8 __attribute__((ext_vector_type(8)));
typedef unsigned short ushortx8 __attribute__((ext_vector_type(8)));
typedef unsigned short ushortx4 __attribute__((ext_vector_type(4)));

__device__ __forceinline__ unsigned short f2b(float f) {
    unsigned int u = __float_as_uint(f);
    unsigned int r = u + 0x7FFFu + ((u >> 16) & 1u);   // RNE
    return (unsigned short)(r >> 16);
}
__device__ __forceinline__ float b2f(unsigned short u) {
    return __uint_as_float(((unsigned int)u) << 16);
}
__device__ __forceinline__ float sigmoidf(float x) {
    return 1.0f / (1.0f + __expf(-x));
}

// async global->LDS, 16 B per lane; lptr must be wave-uniform (HW adds lane*16)
__device__ __forceinline__ void gl_lds16(const unsigned short* g, unsigned short* l) {
    __builtin_amdgcn_global_load_lds(
        (const __attribute__((address_space(1))) void*)g,
        (__attribute__((address_space(3))) void*)l, 16, 0, 0);
}

// ---------------------------------------------------------------------------
// prep_all: one dispatch for all weight/input preprocessing (role by blockIdx).
// ---------------------------------------------------------------------------
__global__ __launch_bounds__(256) void prep_all(
    const float* __restrict__ W_in, const float* __restrict__ W_lat,
    const float* __restrict__ W_out, const float* __restrict__ x,
    unsigned short* __restrict__ WinT, unsigned short* __restrict__ WlatT,
    unsigned short* __restrict__ WoutB, unsigned short* __restrict__ xb)
{
    __shared__ unsigned short t[64][65];
    const int blk = blockIdx.x, tid = threadIdx.x;

    if (blk < 128) {                       // Win transpose
        int bx = (blk & 15) * 64, by = (blk >> 4) * 64;
        int tx = tid & 63, ty = tid >> 6;
        for (int r = ty; r < 64; r += 4)
            t[r][tx] = f2b(W_in[(size_t)(by + r) * 1024 + bx + tx]);
        __syncthreads();
        for (int r = ty; r < 64; r += 4)
            WinT[(size_t)(bx + r) * 512 + by + tx] = t[tx][r];
    } else if (blk < 384) {                // Wlat transpose
        int b2 = blk - 128;
        int bx = (b2 & 15) * 64, by = (b2 >> 4) * 64;
        int tx = tid & 63, ty = tid >> 6;
        for (int r = ty; r < 64; r += 4)
            t[r][tx] = f2b(W_lat[(size_t)(by + r) * 1024 + bx + tx]);
        __syncthreads();
        for (int r = ty; r < 64; r += 4)
            WlatT[(size_t)(bx + r) * 1024 + by + tx] = t[tx][r];
    } else if (blk < 896) {                // Wout convert
        int i = ((blk - 384) * 256 + tid) * 4;
        f32x4 v = *(const f32x4*)(W_out + i);
        ushortx4 o;
        o[0] = f2b(v[0]); o[1] = f2b(v[1]); o[2] = f2b(v[2]); o[3] = f2b(v[3]);
        *(ushortx4*)(WoutB + i) = o;
    } else {                               // x convert
        size_t i8 = (size_t)((blk - 896) * 256 + tid) * 8;
        int m = (int)(i8 >> 9), k = (int)(i8 & 511);
        int b = m & 63, tt = m >> 6;
        const float* src = x + ((size_t)b * 200 + tt) * 512 + k;
        f32x4 v0 = *(const f32x4*)src;
        f32x4 v1 = *(const f32x4*)(src + 4);
        ushortx8 o;
        o[0] = f2b(v0[0]); o[1] = f2b(v0[1]); o[2] = f2b(v0[2]); o[3] = f2b(v0[3]);
        o[4] = f2b(v1[0]); o[5] = f2b(v1[1]); o[6] = f2b(v1[2]); o[7] = f2b(v1[3]);
        *(ushortx8*)(xb + i8) = o;
    }
}

// ---------------------------------------------------------------------------
// NT GEMM (unchanged from R18: XCD-grouped swizzle; MODE 0 bf16 out,
// MODE 2 fp32+bias remapped [B,T,OUT]).
// ---------------------------------------------------------------------------
template<int BM, int BN, int MODE>
__global__ __launch_bounds__(256) void gemm_nt(
    const unsigned short* __restrict__ A,
    const unsigned short* __restrict__ Bt,
    float* __restrict__ outf,
    unsigned short* __restrict__ outb,
    const float* __restrict__ bias,
    int M, int N, int K, int t_base)
{
    constexpr int WM = BM / 2, WN = BN / 2;
    constexpr int TM = WM / 16, TN = WN / 16;

    __shared__ unsigned short Asm[BM * 64];
    __shared__ unsigned short Bsm[BN * 64];

    const int tid  = threadIdx.x;
    const int wave = tid >> 6, lane = tid & 63;
    const int m16  = lane & 15, quad = lane >> 4;
    const int nwg = gridDim.x * gridDim.y;
    const int d   = blockIdx.y * gridDim.x + blockIdx.x;
    const int l   = (d & 7) * (nwg >> 3) + (d >> 3);
    const int bm0 = (l / gridDim.x) * BM, bn0 = (l % gridDim.x) * BN;
    const int wr   = (wave >> 1) * WM, wc = (wave & 1) * WN;
    const int sr   = lane >> 3;
    const int sc   = lane & 7;

    f32x4 acc[TM][TN];
#pragma unroll
    for (int i = 0; i < TM; i++)
#pragma unroll
        for (int j = 0; j < TN; j++)
            acc[i][j] = (f32x4){0.f, 0.f, 0.f, 0.f};

    for (int k0 = 0; k0 < K; k0 += 64) {
#pragma unroll
        for (int g = wave; g < BM / 8; g += 4) {
            int r = g * 8 + sr;
            int c = sc ^ (r & 7);
            gl_lds16(A + (size_t)(bm0 + r) * K + k0 + c * 8, Asm + g * 512);
        }
#pragma unroll
        for (int g = wave; g < BN / 8; g += 4) {
            int r = g * 8 + sr;
            int c = sc ^ (r & 7);
            gl_lds16(Bt + (size_t)(bn0 + r) * K + k0 + c * 8, Bsm + g * 512);
        }
        __syncthreads();

        ushortx8 af[2][TM], bfr[2][TN];
#pragma unroll
        for (int kh = 0; kh < 2; kh++) {
#pragma unroll
            for (int i = 0; i < TM; i++) {
                int ra = wr + i * 16 + m16;
                af[kh][i] = *(const ushortx8*)(
                    Asm + ra * 64 + (((kh * 4 + quad) ^ (ra & 7)) * 8));
            }
#pragma unroll
            for (int j = 0; j < TN; j++) {
                int rb = wc + j * 16 + m16;
                bfr[kh][j] = *(const ushortx8*)(
                    Bsm + rb * 64 + (((kh * 4 + quad) ^ (rb & 7)) * 8));
            }
        }
#pragma unroll
        for (int i = 0; i < TM; i++)
#pragma unroll
            for (int j = 0; j < TN; j++) {
                acc[i][j] = __builtin_amdgcn_mfma_f32_16x16x32_bf16(
                    __builtin_bit_cast(bf16x8, af[0][i]),
                    __builtin_bit_cast(bf16x8, bfr[0][j]),
                    acc[i][j], 0, 0, 0);
                acc[i][j] = __builtin_amdgcn_mfma_f32_16x16x32_bf16(
                    __builtin_bit_cast(bf16x8, af[1][i]),
                    __builtin_bit_cast(bf16x8, bfr[1][j]),
                    acc[i][j], 0, 0, 0);
            }
        __syncthreads();
    }

    // epilogue; C/D layout: col = lane&15, row = quad*4 + reg  (m89-verified)
#pragma unroll
    for (int i = 0; i < TM; i++)
#pragma unroll
        for (int j = 0; j < TN; j++) {
            int col = bn0 + wc + j * 16 + m16;
            float bv = (MODE == 2) ? bias[col] : 0.f;
#pragma unroll
            for (int v = 0; v < 4; v++) {
                int row = bm0 + wr + i * 16 + quad * 4 + v;
                if (MODE == 2) {
                    size_t o = (size_t)((row & 63) * 200 + t_base + (row >> 6)) * N + col;
                    outf[o] = acc[i][j][v] + bv;
                } else {
                    outb[(size_t)row * N + col] = f2b(acc[i][j][v]);
                }
            }
        }
}

// ---------------------------------------------------------------------------
// Fused lateral GEMM + 20-step GLIFR recurrence for one chunk.
// first=1 (chunk 0): skip GEMM; recurrence straight from bf16 x_proj.
// first=0: 3-buffer counted-vmcnt pipeline, BK=128, 8 sub-steps, fully
// unrolled with named buffers X/Y/Z. Each phase: STAGE(next+2) issue ->
// COMPUTE(cur) -> `s_waitcnt vmcnt(9) lgkmcnt(0)` + raw s_barrier.
// 9 = uniform loads/wave/STAGE (A 20/4 + B 16/4); vmcnt retires in issue
// order so the wait guarantees the stage issued 2 phases ago is complete.
// Block tile M=80 (20t x 4b), N=64 h; grid 256 = 1 block/CU. XCD-grouped
// swizzle: XCD k owns b-groups 2k,2k+1. LDS row = 256 B = 16 slots of 16 B;
// slot c of row r holds chunk c^(r&15) (R8-proven). Waves 0,1 rows 0..47
// (TM=3); waves 2,3 rows 48..79 (TM=2); TN=2.
// ---------------------------------------------------------------------------
__global__ __launch_bounds__(256) void fused_chunk(
    const unsigned short* __restrict__ Fprev, // [1280,1024] bf16, rows t*64+b
    const unsigned short* __restrict__ Wlat,  // [1024,1024] bf16 NT
    const unsigned short* __restrict__ xproj, // [1280,1024] bf16 (syn chunk c)
    float* __restrict__ state,                // 4 x [B*H]
    unsigned short* __restrict__ Fc,          // F chunk c out
    const float* __restrict__ thresh,
    const float* __restrict__ t_km,
    const float* __restrict__ t_ak,
    const float* __restrict__ amp,
    const float* __restrict__ t_ar,
    int first)
{
    const int BH = 64 * 1024;
    __shared__ __align__(16) char lds[110592];
    // 3 buffers: A 80*256B = 20480, B 64*256B = 16384 -> 36864 each
    unsigned short* AX = (unsigned short*)lds;
    unsigned short* BX = (unsigned short*)(lds + 20480);
    unsigned short* AY = (unsigned short*)(lds + 36864);
    unsigned short* BY = (unsigned short*)(lds + 57344);
    unsigned short* AZ = (unsigned short*)(lds + 73728);
    unsigned short* BZ = (unsigned short*)(lds + 94208);
    float* synT = (float*)lds;                 // 80*66 f32 = 21120 B overlay

    const int tid  = threadIdx.x;
    const int wave = tid >> 6, lane = tid & 63;
    const int m16  = lane & 15, quad = lane >> 4;
    const int sr4  = lane >> 4;        // row within a 4-row staging group
    const int sc16 = lane & 15;        // LDS 16B slot within the 256B row
    // XCD-grouped swizzle: XCD d%8 gets b-groups 2(d%8), 2(d%8)+1.
    const int d    = blockIdx.y * 16 + blockIdx.x;
    const int l    = (d & 7) * 32 + (d >> 3);
    const int b0   = (l >> 4) * 4, h0 = (l & 15) * 64;
    const int wrow = (wave >> 1) * 48;
    const int wc   = (wave & 1) * 32;

    // recurrence constants
    const int h    = h0 + lane;
    const int gidx = (b0 + wave) * 1024 + h;
    float th  = thresh[h];
    float sm  = sigmoidf(t_km[h]);             // DT*k_m
    float rm  = 0.1f * sm;                     // R_MEM*DT*k_m
    float om  = 1.0f - sm;
    float sa0 = sigmoidf(t_ak[h]);
    float sa1 = sigmoidf(t_ak[1024 + h]);
    float am0 = amp[h];
    float am1 = amp[1024 + h];
    float r0  = 1.0f - 2.0f * sigmoidf(t_ar[h]);
    float r1  = 1.0f - 2.0f * sigmoidf(t_ar[1024 + h]);

    if (first) {
        // ---- chunk 0: recurrence straight from x_proj, zero state ----
        float volt = 0.f, as0 = 0.f, as1 = 0.f, fir = 0.f;
#pragma unroll
        for (int s = 0; s < 20; s++) {
            float sv  = b2f(xproj[(size_t)(s * 64 + b0 + wave) * 1024 + h]);
            float na0 = (am0 + r0 * as0) * fir * sa0 + (1.f - sa0) * as0;
            float na1 = (am1 + r1 * as1) * fir * sa1 + (1.f - sa1) * as1;
            volt = rm * (sv + na0 + na1) + om * volt;
            fir  = sigmoidf(volt - th);
            Fc[(size_t)s * BH + gidx] = f2b(fir);
            as0 = na0; as1 = na1;
        }
        state[gidx]          = volt;
        state[BH + gidx]     = as0;
        state[2 * BH + gidx] = as1;
        state[3 * BH + gidx] = fir;
        return;
    }

    f32x4 acc[3][2];
    // acc init = x_proj tile (bf16); these vmem loads are OLDER than all
    // STAGE loads, so in-order vmcnt retiring keeps counted waits valid.
#pragma unroll
    for (int i = 0; i < 3; i++) {
        if (i < 2 || wave < 2) {
#pragma unroll
            for (int j = 0; j < 2; j++)
#pragma unroll
                for (int v = 0; v < 4; v++) {
                    int row = wrow + i * 16 + quad * 4 + v;
                    int col = h0 + wc + j * 16 + m16;
                    acc[i][j][v] = b2f(
                        xproj[(size_t)(((row >> 2) << 6) + b0 + (row & 3)) * 1024 + col]);
                }
        }
    }

    // stage one K=128 sub-tile; 9 gl_lds16 per wave (A 5, B 4) — uniform.
    auto STAGE = [&](unsigned short* Ad, unsigned short* Bd, int k0) {
        for (int g = wave; g < 20; g += 4) {
            int r = g * 4 + sr4;                        // 0..79
            int c = sc16 ^ (r & 15);                    // global-side swizzle
            int m = ((r >> 2) << 6) + b0 + (r & 3);
            gl_lds16(Fprev + (size_t)m * 1024 + k0 + c * 8, Ad + g * 512);
        }
        for (int g = wave; g < 16; g += 4) {
            int r = g * 4 + sr4;                        // 0..63
            int c = sc16 ^ (r & 15);
            gl_lds16(Wlat + (size_t)(h0 + r) * 1024 + k0 + c * 8, Bd + g * 512);
        }
    };
    // consume one K=128 sub-tile (R8-proven fragment pattern, TM=3/TN=2)
    auto COMPUTE = [&](const unsigned short* As, const unsigned short* Bs) {
        ushortx8 af[4][3], bfr[4][2];
#pragma unroll
        for (int kh = 0; kh < 4; kh++) {
            int s = kh * 4 + quad;                      // k-chunk index 0..15
#pragma unroll
            for (int i = 0; i < 3; i++) {
                if (i < 2 || wave < 2) {
                    int ra = wrow + i * 16 + m16;
                    af[kh][i] = *(const ushortx8*)(
                        As + ra * 128 + ((s ^ (ra & 15)) * 8));
                }
            }
#pragma unroll
            for (int j = 0; j < 2; j++) {
                int rb = wc + j * 16 + m16;
                bfr[kh][j] = *(const ushortx8*)(
                    Bs + rb * 128 + ((s ^ (rb & 15)) * 8));
            }
        }
#pragma unroll
        for (int i = 0; i < 3; i++) {
            if (i < 2 || wave < 2) {
#pragma unroll
                for (int j = 0; j < 2; j++) {
#pragma unroll
                    for (int kh = 0; kh < 4; kh++) {
                        acc[i][j] = __builtin_amdgcn_mfma_f32_16x16x32_bf16(
                            __builtin_bit_cast(bf16x8, af[kh][i]),
                            __builtin_bit_cast(bf16x8, bfr[kh][j]), acc[i][j], 0, 0, 0);
                    }
                }
            }
        }
    };

#define W9B() do { asm volatile("s_waitcnt vmcnt(9) lgkmcnt(0)" ::: "memory"); \
                   __builtin_amdgcn_s_barrier(); } while (0)
#define W0B() do { asm volatile("s_waitcnt vmcnt(0) lgkmcnt(0)" ::: "memory"); \
                   __builtin_amdgcn_s_barrier(); } while (0)

    // 3-buffer counted-vmcnt pipeline, 8 sub-steps of K=128, fully unrolled.
    STAGE(AX, BX, 0);
    STAGE(AY, BY, 128);
    W9B();                                  // X ready (also drains xproj loads)
    STAGE(AZ, BZ, 256);  COMPUTE(AX, BX);  W9B();   // Y ready; Z in flight
    STAGE(AX, BX, 384);  COMPUTE(AY, BY);  W9B();   // Z ready; X in flight
    STAGE(AY, BY, 512);  COMPUTE(AZ, BZ);  W9B();   // X ready
    STAGE(AZ, BZ, 640);  COMPUTE(AX, BX);  W9B();   // Y ready
    STAGE(AX, BX, 768);  COMPUTE(AY, BY);  W9B();   // Z ready
    STAGE(AY, BY, 896);  COMPUTE(AZ, BZ);  W9B();   // X ready
                         COMPUTE(AX, BX);  W0B();   // Y ready (drain last stage)
                         COMPUTE(AY, BY);
    __syncthreads();

#undef W9B
#undef W0B

    // spill syn tile to LDS (overlays buffer X; safe after final barrier).
    // stride 66 words: quads land 8 banks apart -> 2-way (free) on write+read.
#pragma unroll
    for (int i = 0; i < 3; i++) {
        if (i < 2 || wave < 2) {
#pragma unroll
            for (int j = 0; j < 2; j++)
#pragma unroll
                for (int v = 0; v < 4; v++) {
                    int row = wrow + i * 16 + quad * 4 + v;
                    synT[row * 66 + wc + j * 16 + m16] = acc[i][j][v];
                }
        }
    }
    __syncthreads();

    // 20-step recurrence: thread -> (b = wave, h = lane)
    float volt = state[gidx];
    float as0  = state[BH + gidx];
    float as1  = state[2 * BH + gidx];
    float fir  = state[3 * BH + gidx];

#pragma unroll
    for (int s = 0; s < 20; s++) {
        float sv  = synT[(s * 4 + wave) * 66 + lane];
        float na0 = (am0 + r0 * as0) * fir * sa0 + (1.f - sa0) * as0;
        float na1 = (am1 + r1 * as1) * fir * sa1 + (1.f - sa1) * as1;
        volt = rm * (sv + na0 + na1) + om * volt;
        fir  = sigmoidf(volt - th);
        Fc[(size_t)s * BH + gidx] = f2b(fir);
        as0 = na0; as1 = na1;
    }
    state[gidx]          = volt;
    state[BH + gidx]     = as0;
    state[2 * BH + gidx] = as1;
    state[3 * BH + gidx] = fir;
}

// ---------------------------------------------------------------------------
extern "C" void kernel_launch(void* const* d_in, const int* in_sizes, int n_in,
                              void* d_out, int out_size, void* d_ws, size_t ws_size,
                              hipStream_t stream)
{
    const float* x      = (const float*)d_in[0];  // [64,200,512]
    const float* W_in   = (const float*)d_in[1];  // [512,1024]
    const float* W_lat  = (const float*)d_in[2];  // [1024,1024]
    const float* thresh = (const float*)d_in[3];  // [1,1024]
    const float* t_km   = (const float*)d_in[4];  // [1,1024]
    const float* t_ak   = (const float*)d_in[5];  // [2,1,1024]
    const float* amp    = (const float*)d_in[6];  // [2,1,1024]
    const float* t_ar   = (const float*)d_in[7];  // [2,1,1024]
    const float* W_out  = (const float*)d_in[8];  // [512,1024] (n,k) already!
    const float* b_out  = (const float*)d_in[9];  // [512]
    float* out = (float*)d_out;                   // [64,200,512]

    char* ws = (char*)d_ws;
    unsigned short* synb  = (unsigned short*)ws;            // [T,B,H] bf16 x_proj
    float*          state = (float*)(ws + 52428800);
    unsigned short* F     = (unsigned short*)(ws + 53477376);
    unsigned short* xb    = F;  // overlay: dead before first F write
    unsigned short* WinT  = (unsigned short*)(ws + 79691776);
    unsigned short* WlatT = (unsigned short*)(ws + 80740352);
    unsigned short* WoutB = (unsigned short*)(ws + 82837504);

    // Prep (one dispatch): transposes/converts to bf16 NT layout, x to m-order.
    prep_all<<<4096, 256, 0, stream>>>(W_in, W_lat, W_out, x,
                                       WinT, WlatT, WoutB, xb);

    // x_proj (= synb bf16, read-only from here on): [12800,1024] = xb @ WinT^T
    gemm_nt<128, 128, 0><<<dim3(1024 / 128, 12800 / 128), 256, 0, stream>>>(
        xb, WinT, nullptr, synb, nullptr, 12800, 1024, 512, 0);

    const size_t CHUNK = 20 * 64 * 1024;  // elements per chunk of [T,B,H]
    // chunk 0 (first=1: no lateral term, zero state) then chunks 1..9
    fused_chunk<<<dim3(16, 16), 256, 0, stream>>>(
        F, WlatT, synb, state, F, thresh, t_km, t_ak, amp, t_ar, 1);
    for (int c = 1; c < 10; c++) {
        fused_chunk<<<dim3(16, 16), 256, 0, stream>>>(
            F + (size_t)(c - 1) * CHUNK, WlatT,
            synb + (size_t)c * CHUNK, state, F + (size_t)c * CHUNK,
            thresh, t_km, t_ak, amp, t_ar, 0);
    }

    // readout: out[b,t,:] = F[t,b,:] @ W_out^T + b_out  (W_out already [n,k])
    gemm_nt<128, 128, 2><<<dim3(512 / 128, 12800 / 128), 256, 0, stream>>>(
        F, WoutB, out, nullptr, b_out, 12800, 512, 1024, 0);
}